// Round 1
// baseline (6472.147 us; speedup 1.0000x reference)
//
#include <hip/hip_runtime.h>
#include <hip/hip_bf16.h>

#define NN 50000
#define EE 1600000
#define NEDGE (EE + NN)   // with self loops
#define HH 4
#define CC 32
#define HC 128
#define GG 64

// ---- monotone float<->uint encoding for atomicMax on floats ----
__device__ __forceinline__ unsigned fenc(float f) {
    unsigned u = __float_as_uint(f);
    return (u & 0x80000000u) ? ~u : (u | 0x80000000u);
}
__device__ __forceinline__ float fdec(unsigned u) {
    return (u & 0x80000000u) ? __uint_as_float(u & 0x7FFFFFFFu) : __uint_as_float(~u);
}

// xw = X @ W  (N x 128 @ 128 x 128), plus per-head alpha dots
__global__ __launch_bounds__(128) void gemm_alpha(
    const float* __restrict__ X, const float* __restrict__ W,
    const float* __restrict__ a_src, const float* __restrict__ a_dst,
    float* __restrict__ xw, float* __restrict__ as_, float* __restrict__ ad_) {
    int n = blockIdx.x;
    int j = threadIdx.x;
    __shared__ float xs[HC];
    xs[j] = X[(size_t)n * HC + j];
    __syncthreads();
    float acc = 0.f;
#pragma unroll 8
    for (int k = 0; k < HC; ++k) acc = fmaf(xs[k], W[k * HC + j], acc);
    xw[(size_t)n * HC + j] = acc;
    float ps = acc * a_src[j];
    float pd = acc * a_dst[j];
#pragma unroll
    for (int off = 16; off > 0; off >>= 1) {
        ps += __shfl_down(ps, off, 32);
        pd += __shfl_down(pd, off, 32);
    }
    if ((j & 31) == 0) {
        as_[n * HH + (j >> 5)] = ps;
        ad_[n * HH + (j >> 5)] = pd;
    }
}

// pass 1 over edges: segment max of leaky_relu(as[src]+ad[dst]) into menc[dst]
__global__ __launch_bounds__(256) void edge_max(
    const int* __restrict__ ei,
    const float* __restrict__ as_, const float* __restrict__ ad_,
    unsigned* __restrict__ menc) {
    int i = blockIdx.x * 256 + threadIdx.x;
    if (i >= NEDGE) return;
    int s, d;
    if (i < EE) { s = ei[i]; d = ei[EE + i]; } else { s = d = i - EE; }
    float4 a = ((const float4*)as_)[s];
    float4 b = ((const float4*)ad_)[d];
    float e0 = a.x + b.x, e1 = a.y + b.y, e2 = a.z + b.z, e3 = a.w + b.w;
    e0 = e0 > 0.f ? e0 : 0.2f * e0;
    e1 = e1 > 0.f ? e1 : 0.2f * e1;
    e2 = e2 > 0.f ? e2 : 0.2f * e2;
    e3 = e3 > 0.f ? e3 : 0.2f * e3;
    unsigned* md = menc + (size_t)d * HH;
    atomicMax(md + 0, fenc(e0));
    atomicMax(md + 1, fenc(e1));
    atomicMax(md + 2, fenc(e2));
    atomicMax(md + 3, fenc(e3));
}

// pass 2 over edges: denom[dst][h] += w ; acc[dst][:] += w * xw[src][:]
// 32 threads per edge, thread t handles cols 4t..4t+3 (head t/8)
__global__ __launch_bounds__(256) void edge_acc(
    const int* __restrict__ ei,
    const float* __restrict__ as_, const float* __restrict__ ad_,
    const unsigned* __restrict__ menc, const float* __restrict__ xw,
    float* __restrict__ denom, float* __restrict__ acc) {
    int gid = blockIdx.x * 256 + threadIdx.x;
    int i = gid >> 5;
    if (i >= NEDGE) return;
    int t = threadIdx.x & 31;
    int s, d;
    if (i < EE) { s = ei[i]; d = ei[EE + i]; } else { s = d = i - EE; }
    int h = t >> 3;
    float e = as_[s * HH + h] + ad_[d * HH + h];
    e = e > 0.f ? e : 0.2f * e;
    float m = fdec(menc[(size_t)d * HH + h]);
    float w = __expf(e - m);
    if ((t & 7) == 0) atomicAdd(&denom[(size_t)d * HH + h], w);
    float4 v = ((const float4*)xw)[(size_t)s * (HC / 4) + t];
    float* dst = acc + (size_t)d * HC + t * 4;
    atomicAdd(dst + 0, w * v.x);
    atomicAdd(dst + 1, w * v.y);
    atomicAdd(dst + 2, w * v.z);
    atomicAdd(dst + 3, w * v.w);
}

// acc = elu(acc/denom + b), in place
__global__ __launch_bounds__(256) void finalize_node(
    float* __restrict__ acc, const float* __restrict__ denom,
    const float* __restrict__ b) {
    size_t i = (size_t)blockIdx.x * 256 + threadIdx.x;
    if (i >= (size_t)NN * HC) return;
    int n = (int)(i >> 7);
    int j = (int)(i & 127);
    int h = j >> 5;
    float v = acc[i] / denom[n * HH + h] + b[j];
    acc[i] = v > 0.f ? v : expm1f(v);
}

// sorted-batch mean pool, run-length accumulate then few atomics
__global__ __launch_bounds__(128) void pool(
    const float* __restrict__ h1, const int* __restrict__ batch,
    float* __restrict__ sums, float* __restrict__ cnts) {
    int j = threadIdx.x;
    int n0 = blockIdx.x * 64;
    int n1 = n0 + 64; if (n1 > NN) n1 = NN;
    if (n0 >= NN) return;
    int cur = batch[n0];
    float local = 0.f;
    int cnt = 0;
    for (int n = n0; n < n1; ++n) {
        int g = batch[n];
        if (g != cur) {
            atomicAdd(&sums[cur * HC + j], local);
            if (j == 0) atomicAdd(&cnts[cur], (float)cnt);
            local = 0.f; cnt = 0; cur = g;
        }
        local += h1[(size_t)n * HC + j];
        ++cnt;
    }
    atomicAdd(&sums[cur * HC + j], local);
    if (j == 0) atomicAdd(&cnts[cur], (float)cnt);
}

__global__ __launch_bounds__(128) void head_out(
    const float* __restrict__ sums, const float* __restrict__ cnts,
    const float* __restrict__ lin_w, const float* __restrict__ lin_b,
    float* __restrict__ out) {
    int g = blockIdx.x;
    int j = threadIdx.x;
    float c = cnts[g];
    c = c > 1.f ? c : 1.f;
    float v = sums[g * HC + j] / c * lin_w[j];
    __shared__ float red[HC];
    red[j] = v;
    __syncthreads();
    for (int off = 64; off > 0; off >>= 1) {
        if (j < off) red[j] += red[j + off];
        __syncthreads();
    }
    if (j == 0) out[g] = red[0] + lin_b[0];
}

extern "C" void kernel_launch(void* const* d_in, const int* in_sizes, int n_in,
                              void* d_out, int out_size, void* d_ws, size_t ws_size,
                              hipStream_t stream) {
    const float* x   = (const float*)d_in[0];
    const int*   ei  = (const int*)d_in[1];
    const int*   bat = (const int*)d_in[2];
    const float* W0  = (const float*)d_in[3];
    const float* as0 = (const float*)d_in[4];
    const float* ad0 = (const float*)d_in[5];
    const float* b0  = (const float*)d_in[6];
    const float* W1  = (const float*)d_in[7];
    const float* as1 = (const float*)d_in[8];
    const float* ad1 = (const float*)d_in[9];
    const float* b1  = (const float*)d_in[10];
    const float* lw  = (const float*)d_in[11];
    const float* lb  = (const float*)d_in[12];
    float* out = (float*)d_out;

    char* w = (char*)d_ws;
    float* xw   = (float*)w;  w += (size_t)NN * HC * 4;
    float* as_  = (float*)w;  w += (size_t)NN * HH * 4;
    float* ad_  = (float*)w;  w += (size_t)NN * HH * 4;
    unsigned* menc = (unsigned*)w; w += (size_t)NN * HH * 4;
    float* denom = (float*)w; w += (size_t)NN * HH * 4;
    float* acc0 = (float*)w;  w += (size_t)NN * HC * 4;
    float* acc1 = (float*)w;  w += (size_t)NN * HC * 4;
    float* sums = (float*)w;  w += (size_t)GG * HC * 4;
    float* cnts = (float*)w;  w += (size_t)GG * 4;

    const int eb = (NEDGE + 255) / 256;
    const int ab = (NEDGE * 32 + 255) / 256;
    const int fb = ((int)((size_t)NN * HC) + 255) / 256;

    // ---- layer 0 ----
    gemm_alpha<<<NN, 128, 0, stream>>>(x, W0, as0, ad0, xw, as_, ad_);
    hipMemsetAsync(menc, 0, (size_t)NN * HH * 4, stream);
    hipMemsetAsync(denom, 0, (size_t)NN * HH * 4, stream);
    hipMemsetAsync(acc0, 0, (size_t)NN * HC * 4, stream);
    edge_max<<<eb, 256, 0, stream>>>(ei, as_, ad_, menc);
    edge_acc<<<ab, 256, 0, stream>>>(ei, as_, ad_, menc, xw, denom, acc0);
    finalize_node<<<fb, 256, 0, stream>>>(acc0, denom, b0);

    // ---- layer 1 ----
    gemm_alpha<<<NN, 128, 0, stream>>>(acc0, W1, as1, ad1, xw, as_, ad_);
    hipMemsetAsync(menc, 0, (size_t)NN * HH * 4, stream);
    hipMemsetAsync(denom, 0, (size_t)NN * HH * 4, stream);
    hipMemsetAsync(acc1, 0, (size_t)NN * HC * 4, stream);
    edge_max<<<eb, 256, 0, stream>>>(ei, as_, ad_, menc);
    edge_acc<<<ab, 256, 0, stream>>>(ei, as_, ad_, menc, xw, denom, acc1);
    finalize_node<<<fb, 256, 0, stream>>>(acc1, denom, b1);

    // ---- pool + head ----
    hipMemsetAsync(sums, 0, ((size_t)GG * HC + GG) * 4, stream);
    pool<<<(NN + 63) / 64, 128, 0, stream>>>(acc1, bat, sums, cnts);
    head_out<<<GG, 128, 0, stream>>>(sums, cnts, lw, lb, out);
}

// Round 2
// 662.644 us; speedup vs baseline: 9.7672x; 9.7672x over previous
//
#include <hip/hip_runtime.h>
#include <hip/hip_bf16.h>

#define NN 50000
#define EE 1600000
#define NEDGE (EE + NN)   // with self loops
#define HH 4
#define HC 128
#define GG 64
#define MT 32             // nodes per gemm block

__device__ __forceinline__ float lrelu(float x) { return x > 0.f ? x : 0.2f * x; }

// ---------------- CSR build ----------------
__global__ __launch_bounds__(256) void hist(const int* __restrict__ ei, int* __restrict__ deg) {
    int i = blockIdx.x * 256 + threadIdx.x;
    if (i >= NEDGE) return;
    int d = (i < EE) ? ei[EE + i] : (i - EE);
    atomicAdd(&deg[d], 1);
}

__global__ __launch_bounds__(1024) void scan_deg(const int* __restrict__ deg, int* __restrict__ row_start) {
    __shared__ int buf[1024];
    __shared__ int carry;
    int tid = threadIdx.x;
    if (tid == 0) carry = 0;
    __syncthreads();
    for (int base = 0; base < NN; base += 1024) {
        int i = base + tid;
        int v = (i < NN) ? deg[i] : 0;
        buf[tid] = v;
        __syncthreads();
        for (int off = 1; off < 1024; off <<= 1) {
            int t = (tid >= off) ? buf[tid - off] : 0;
            __syncthreads();
            buf[tid] += t;
            __syncthreads();
        }
        if (i < NN) row_start[i] = carry + buf[tid] - v;  // exclusive
        __syncthreads();
        if (tid == 0) carry += buf[1023];
        __syncthreads();
    }
    if (tid == 0) row_start[NN] = NEDGE;
}

__global__ __launch_bounds__(256) void scatter(const int* __restrict__ ei, int* __restrict__ cursor,
                                               int* __restrict__ esrc) {
    int i = blockIdx.x * 256 + threadIdx.x;
    if (i >= NEDGE) return;
    int s, d;
    if (i < EE) { s = ei[i]; d = ei[EE + i]; } else { s = d = i - EE; }
    int pos = atomicAdd(&cursor[d], 1);
    esrc[pos] = s;
}

// ---------------- GEMM (X @ W) + per-head alpha dots ----------------
// 32 nodes per block, 256 threads. W staged in LDS once per block.
__global__ __launch_bounds__(256) void gemm_alpha(
    const float* __restrict__ X, const float* __restrict__ W,
    const float* __restrict__ a_src, const float* __restrict__ a_dst,
    float* __restrict__ xw, float* __restrict__ as_, float* __restrict__ ad_) {
    __shared__ float ws[HC][HC];   // 64 KB
    __shared__ float xs[MT][HC];   // 16 KB
    int tid = threadIdx.x;
    int n0 = blockIdx.x * MT;
    {
        const float4* Wv = (const float4*)W;
        float4* wsv = (float4*)&ws[0][0];
        for (int i = tid; i < HC * HC / 4; i += 256) wsv[i] = Wv[i];
    }
    for (int i = tid; i < MT * HC / 4; i += 256) {
        int r = i >> 5, c = i & 31;
        int n = n0 + r;
        float4 v = (n < NN) ? ((const float4*)X)[(size_t)n * (HC / 4) + c]
                            : make_float4(0.f, 0.f, 0.f, 0.f);
        ((float4*)&xs[r][0])[c] = v;
    }
    __syncthreads();

    int jg = tid & 31;   // cols jg*4 .. jg*4+3
    int ng = tid >> 5;   // nodes ng*4 .. ng*4+3
    float4 acc[4] = {};
    for (int k = 0; k < HC; k += 4) {
        float4 xv[4];
#pragma unroll
        for (int r = 0; r < 4; ++r) xv[r] = *(const float4*)&xs[ng * 4 + r][k];
#pragma unroll
        for (int dk = 0; dk < 4; ++dk) {
            float4 wv = *(const float4*)&ws[k + dk][jg * 4];
#pragma unroll
            for (int r = 0; r < 4; ++r) {
                float xk = (dk == 0 ? xv[r].x : dk == 1 ? xv[r].y : dk == 2 ? xv[r].z : xv[r].w);
                acc[r].x = fmaf(xk, wv.x, acc[r].x);
                acc[r].y = fmaf(xk, wv.y, acc[r].y);
                acc[r].z = fmaf(xk, wv.z, acc[r].z);
                acc[r].w = fmaf(xk, wv.w, acc[r].w);
            }
        }
    }
    float4 asv = ((const float4*)a_src)[jg];
    float4 adv = ((const float4*)a_dst)[jg];
#pragma unroll
    for (int r = 0; r < 4; ++r) {
        int n = n0 + ng * 4 + r;
        float ps = acc[r].x * asv.x + acc[r].y * asv.y + acc[r].z * asv.z + acc[r].w * asv.w;
        float pd = acc[r].x * adv.x + acc[r].y * adv.y + acc[r].z * adv.z + acc[r].w * adv.w;
        ps += __shfl_xor(ps, 1); pd += __shfl_xor(pd, 1);
        ps += __shfl_xor(ps, 2); pd += __shfl_xor(pd, 2);
        ps += __shfl_xor(ps, 4); pd += __shfl_xor(pd, 4);
        if (n < NN) {
            ((float4*)xw)[(size_t)n * (HC / 4) + jg] = acc[r];
            if ((jg & 7) == 0) {
                int h = jg >> 3;
                as_[n * HH + h] = ps;
                ad_[n * HH + h] = pd;
            }
        }
    }
}

// ---------------- fused segment softmax + aggregate + bias + ELU ----------------
// one 64-lane wave per destination node; no atomics
__global__ __launch_bounds__(256) void aggregate(
    const int* __restrict__ esrc, const int* __restrict__ row_start,
    const float* __restrict__ as_, const float* __restrict__ ad_,
    const float* __restrict__ xw, const float* __restrict__ bias,
    float* __restrict__ out) {
    int node = blockIdx.x * 4 + (int)(threadIdx.x >> 6);
    if (node >= NN) return;
    int lane = threadIdx.x & 63;
    int beg = row_start[node];
    int end = row_start[node + 1];
    float4 ad = ((const float4*)ad_)[node];

    // pass 1: per-head max
    float m0 = -1e30f, m1 = -1e30f, m2 = -1e30f, m3 = -1e30f;
    for (int i = beg + lane; i < end; i += 64) {
        float4 av = ((const float4*)as_)[esrc[i]];
        m0 = fmaxf(m0, lrelu(av.x + ad.x));
        m1 = fmaxf(m1, lrelu(av.y + ad.y));
        m2 = fmaxf(m2, lrelu(av.z + ad.z));
        m3 = fmaxf(m3, lrelu(av.w + ad.w));
    }
#pragma unroll
    for (int off = 32; off; off >>= 1) {
        m0 = fmaxf(m0, __shfl_xor(m0, off));
        m1 = fmaxf(m1, __shfl_xor(m1, off));
        m2 = fmaxf(m2, __shfl_xor(m2, off));
        m3 = fmaxf(m3, __shfl_xor(m3, off));
    }

    // pass 2: weights + weighted gather
    int h = lane >> 4;                 // head of cols 2*lane, 2*lane+1
    float2 acc = make_float2(0.f, 0.f);
    float d0 = 0.f, d1 = 0.f, d2 = 0.f, d3 = 0.f;
    for (int base = beg; base < end; base += 64) {
        int i = base + lane;
        int s = 0;
        float w0 = 0.f, w1 = 0.f, w2 = 0.f, w3 = 0.f;
        if (i < end) {
            s = esrc[i];
            float4 av = ((const float4*)as_)[s];
            w0 = __expf(lrelu(av.x + ad.x) - m0);
            w1 = __expf(lrelu(av.y + ad.y) - m1);
            w2 = __expf(lrelu(av.z + ad.z) - m2);
            w3 = __expf(lrelu(av.w + ad.w) - m3);
            d0 += w0; d1 += w1; d2 += w2; d3 += w3;
        }
        int cnt = end - base; if (cnt > 64) cnt = 64;
        for (int j = 0; j < cnt; ++j) {
            int sj = __shfl(s, j);
            float w0j = __shfl(w0, j);
            float w1j = __shfl(w1, j);
            float w2j = __shfl(w2, j);
            float w3j = __shfl(w3, j);
            float wj = h == 0 ? w0j : (h == 1 ? w1j : (h == 2 ? w2j : w3j));
            float2 v = ((const float2*)xw)[(size_t)sj * 64 + lane];
            acc.x = fmaf(wj, v.x, acc.x);
            acc.y = fmaf(wj, v.y, acc.y);
        }
    }
#pragma unroll
    for (int off = 32; off; off >>= 1) {
        d0 += __shfl_xor(d0, off);
        d1 += __shfl_xor(d1, off);
        d2 += __shfl_xor(d2, off);
        d3 += __shfl_xor(d3, off);
    }
    float dn = h == 0 ? d0 : (h == 1 ? d1 : (h == 2 ? d2 : d3));
    float2 bb = ((const float2*)bias)[lane];
    float ox = acc.x / dn + bb.x;
    float oy = acc.y / dn + bb.y;
    ox = ox > 0.f ? ox : expm1f(ox);
    oy = oy > 0.f ? oy : expm1f(oy);
    ((float2*)out)[(size_t)node * 64 + lane] = make_float2(ox, oy);
}

// ---------------- pooling + head ----------------
__global__ __launch_bounds__(128) void pool(
    const float* __restrict__ h1, const int* __restrict__ batch,
    float* __restrict__ sums, float* __restrict__ cnts) {
    int j = threadIdx.x;
    int n0 = blockIdx.x * 64;
    int n1 = n0 + 64; if (n1 > NN) n1 = NN;
    if (n0 >= NN) return;
    int cur = batch[n0];
    float local = 0.f;
    int cnt = 0;
    for (int n = n0; n < n1; ++n) {
        int g = batch[n];
        if (g != cur) {
            atomicAdd(&sums[cur * HC + j], local);
            if (j == 0) atomicAdd(&cnts[cur], (float)cnt);
            local = 0.f; cnt = 0; cur = g;
        }
        local += h1[(size_t)n * HC + j];
        ++cnt;
    }
    atomicAdd(&sums[cur * HC + j], local);
    if (j == 0) atomicAdd(&cnts[cur], (float)cnt);
}

__global__ __launch_bounds__(128) void head_out(
    const float* __restrict__ sums, const float* __restrict__ cnts,
    const float* __restrict__ lin_w, const float* __restrict__ lin_b,
    float* __restrict__ out) {
    int g = blockIdx.x;
    int j = threadIdx.x;
    float c = cnts[g];
    c = c > 1.f ? c : 1.f;
    float v = sums[g * HC + j] / c * lin_w[j];
    __shared__ float red[HC];
    red[j] = v;
    __syncthreads();
    for (int off = 64; off > 0; off >>= 1) {
        if (j < off) red[j] += red[j + off];
        __syncthreads();
    }
    if (j == 0) out[g] = red[0] + lin_b[0];
}

extern "C" void kernel_launch(void* const* d_in, const int* in_sizes, int n_in,
                              void* d_out, int out_size, void* d_ws, size_t ws_size,
                              hipStream_t stream) {
    const float* x   = (const float*)d_in[0];
    const int*   ei  = (const int*)d_in[1];
    const int*   bat = (const int*)d_in[2];
    const float* W0  = (const float*)d_in[3];
    const float* as0 = (const float*)d_in[4];
    const float* ad0 = (const float*)d_in[5];
    const float* b0  = (const float*)d_in[6];
    const float* W1  = (const float*)d_in[7];
    const float* as1 = (const float*)d_in[8];
    const float* ad1 = (const float*)d_in[9];
    const float* b1  = (const float*)d_in[10];
    const float* lw  = (const float*)d_in[11];
    const float* lb  = (const float*)d_in[12];
    float* out = (float*)d_out;

    char* w = (char*)d_ws;
    float* xw  = (float*)w;  w += (size_t)NN * HC * 4;   // 25.6 MB
    float* h0  = (float*)w;  w += (size_t)NN * HC * 4;   // 25.6 MB (layer0 out, reused for layer1 out)
    float* as_ = (float*)w;  w += (size_t)NN * HH * 4;
    float* ad_ = (float*)w;  w += (size_t)NN * HH * 4;
    int* deg       = (int*)w; w += (size_t)NN * 4;
    int* row_start = (int*)w; w += (size_t)(NN + 1) * 4;
    int* cursor    = (int*)w; w += (size_t)NN * 4;
    int* esrc      = (int*)w; w += (size_t)NEDGE * 4;    // 6.6 MB
    float* sums = (float*)w; w += (size_t)GG * HC * 4;
    float* cnts = (float*)w; w += (size_t)GG * 4;

    const int eb = (NEDGE + 255) / 256;
    const int gb = (NN + MT - 1) / MT;
    const int ab = (NN + 3) / 4;

    // ---- CSR build (once, reused by both layers) ----
    hipMemsetAsync(deg, 0, (size_t)NN * 4, stream);
    hist<<<eb, 256, 0, stream>>>(ei, deg);
    scan_deg<<<1, 1024, 0, stream>>>(deg, row_start);
    hipMemcpyAsync(cursor, row_start, (size_t)NN * 4, hipMemcpyDeviceToDevice, stream);
    scatter<<<eb, 256, 0, stream>>>(ei, cursor, esrc);

    // ---- layer 0 ----
    gemm_alpha<<<gb, 256, 0, stream>>>(x, W0, as0, ad0, xw, as_, ad_);
    aggregate<<<ab, 256, 0, stream>>>(esrc, row_start, as_, ad_, xw, b0, h0);

    // ---- layer 1 ----
    gemm_alpha<<<gb, 256, 0, stream>>>(h0, W1, as1, ad1, xw, as_, ad_);
    aggregate<<<ab, 256, 0, stream>>>(esrc, row_start, as_, ad_, xw, b1, h0);

    // ---- pool + head ----
    hipMemsetAsync(sums, 0, ((size_t)GG * HC + GG) * 4, stream);
    pool<<<(NN + 63) / 64, 128, 0, stream>>>(h0, bat, sums, cnts);
    head_out<<<GG, 128, 0, stream>>>(sums, cnts, lw, lb, out);
}

// Round 3
// 619.255 us; speedup vs baseline: 10.4515x; 1.0701x over previous
//
#include <hip/hip_runtime.h>
#include <hip/hip_bf16.h>

#define NN 50000
#define EE 1600000
#define NEDGE (EE + NN)   // with self loops
#define HH 4
#define HC 128
#define GG 64
#define GMT 64            // nodes per gemm block

__device__ __forceinline__ float lrelu(float x) { return x > 0.f ? x : 0.2f * x; }

// ---------------- CSR build ----------------
__global__ __launch_bounds__(256) void hist(const int* __restrict__ ei, int* __restrict__ deg) {
    int i = blockIdx.x * 256 + threadIdx.x;
    if (i >= NEDGE) return;
    int d = (i < EE) ? ei[EE + i] : (i - EE);
    atomicAdd(&deg[d], 1);
}

// one block; each thread owns a contiguous chunk; writes row_start AND cursor
__global__ __launch_bounds__(1024) void scan_deg(const int* __restrict__ deg,
                                                 int* __restrict__ row_start,
                                                 int* __restrict__ cursor) {
    __shared__ int sums[1024];
    int t = threadIdx.x;
    const int per = (NN + 1023) / 1024;
    int lo = t * per, hi = lo + per; if (hi > NN) hi = NN;
    int s = 0;
    for (int i = lo; i < hi; ++i) s += deg[i];
    sums[t] = s;
    __syncthreads();
    for (int off = 1; off < 1024; off <<= 1) {
        int v = (t >= off) ? sums[t - off] : 0;
        __syncthreads();
        sums[t] += v;
        __syncthreads();
    }
    int run = sums[t] - s;   // exclusive prefix for this chunk
    for (int i = lo; i < hi; ++i) {
        row_start[i] = run;
        cursor[i] = run;
        run += deg[i];
    }
    if (t == 0) row_start[NN] = NEDGE;
}

__global__ __launch_bounds__(256) void scatter(const int* __restrict__ ei, int* __restrict__ cursor,
                                               int* __restrict__ esrc) {
    int i = blockIdx.x * 256 + threadIdx.x;
    if (i >= NEDGE) return;
    int s, d;
    if (i < EE) { s = ei[i]; d = ei[EE + i]; } else { s = d = i - EE; }
    int pos = atomicAdd(&cursor[d], 1);
    esrc[pos] = s;
}

// ---------------- GEMM (X @ W) + per-head alpha dots ----------------
// 64 nodes/block, 256 threads. X tile in LDS (padded); W read through L2.
__global__ __launch_bounds__(256) void gemm_alpha(
    const float* __restrict__ X, const float* __restrict__ W,
    const float* __restrict__ a_src, const float* __restrict__ a_dst,
    float* __restrict__ xw, float* __restrict__ as_, float* __restrict__ ad_) {
    __shared__ float xs[GMT][HC + 4];   // 64 x 132, ~33.8 KB
    int tid = threadIdx.x;
    int n0 = blockIdx.x * GMT;
    for (int i = tid; i < GMT * (HC / 4); i += 256) {
        int r = i >> 5, c4 = i & 31;
        int n = n0 + r;
        float4 v = (n < NN) ? ((const float4*)X)[(size_t)n * 32 + c4]
                            : make_float4(0.f, 0.f, 0.f, 0.f);
        *(float4*)&xs[r][c4 * 4] = v;
    }
    __syncthreads();

    int jg = tid & 31;   // cols jg*4..jg*4+3
    int ng = tid >> 5;   // node group: nodes ng*8..ng*8+7
    float4 acc[8] = {};
    for (int k = 0; k < HC; k += 4) {
        float4 wr[4];
#pragma unroll
        for (int dk = 0; dk < 4; ++dk) wr[dk] = ((const float4*)W)[(k + dk) * 32 + jg];
#pragma unroll
        for (int r = 0; r < 8; ++r) {
            float4 xv = *(const float4*)&xs[ng * 8 + r][k];
            acc[r].x = fmaf(xv.x, wr[0].x, acc[r].x);
            acc[r].y = fmaf(xv.x, wr[0].y, acc[r].y);
            acc[r].z = fmaf(xv.x, wr[0].z, acc[r].z);
            acc[r].w = fmaf(xv.x, wr[0].w, acc[r].w);
            acc[r].x = fmaf(xv.y, wr[1].x, acc[r].x);
            acc[r].y = fmaf(xv.y, wr[1].y, acc[r].y);
            acc[r].z = fmaf(xv.y, wr[1].z, acc[r].z);
            acc[r].w = fmaf(xv.y, wr[1].w, acc[r].w);
            acc[r].x = fmaf(xv.z, wr[2].x, acc[r].x);
            acc[r].y = fmaf(xv.z, wr[2].y, acc[r].y);
            acc[r].z = fmaf(xv.z, wr[2].z, acc[r].z);
            acc[r].w = fmaf(xv.z, wr[2].w, acc[r].w);
            acc[r].x = fmaf(xv.w, wr[3].x, acc[r].x);
            acc[r].y = fmaf(xv.w, wr[3].y, acc[r].y);
            acc[r].z = fmaf(xv.w, wr[3].z, acc[r].z);
            acc[r].w = fmaf(xv.w, wr[3].w, acc[r].w);
        }
    }
    float4 asv = ((const float4*)a_src)[jg];
    float4 adv = ((const float4*)a_dst)[jg];
#pragma unroll
    for (int r = 0; r < 8; ++r) {
        int n = n0 + ng * 8 + r;
        float ps = acc[r].x * asv.x + acc[r].y * asv.y + acc[r].z * asv.z + acc[r].w * asv.w;
        float pd = acc[r].x * adv.x + acc[r].y * adv.y + acc[r].z * adv.z + acc[r].w * adv.w;
        ps += __shfl_xor(ps, 1); pd += __shfl_xor(pd, 1);
        ps += __shfl_xor(ps, 2); pd += __shfl_xor(pd, 2);
        ps += __shfl_xor(ps, 4); pd += __shfl_xor(pd, 4);
        if (n < NN) {
            ((float4*)xw)[(size_t)n * 32 + jg] = acc[r];
            if ((jg & 7) == 0) {
                int h = jg >> 3;
                as_[n * HH + h] = ps;
                ad_[n * HH + h] = pd;
            }
        }
    }
}

// ---------------- fused segment softmax + aggregate + bias + ELU ----------------
// one 64-lane wave per destination node; no atomics; LDS-staged (s,w)
#define SWSTR 66   // float2 stride per head (conflict-free)
__global__ __launch_bounds__(256) void aggregate(
    const int* __restrict__ esrc, const int* __restrict__ row_start,
    const float* __restrict__ as_, const float* __restrict__ ad_,
    const float* __restrict__ xw, const float* __restrict__ bias,
    float* __restrict__ out) {
    __shared__ float2 sw_all[4][4 * SWSTR];
    int wid = (int)(threadIdx.x >> 6);
    int node = blockIdx.x * 4 + wid;
    if (node >= NN) return;
    int lane = threadIdx.x & 63;
    float2* sw = &sw_all[wid][0];
    int beg = row_start[node];
    int end = row_start[node + 1];
    float4 ad = ((const float4*)ad_)[node];

    // pass 1: per-head max
    float m0 = -1e30f, m1 = -1e30f, m2 = -1e30f, m3 = -1e30f;
    for (int i = beg + lane; i < end; i += 64) {
        float4 av = ((const float4*)as_)[esrc[i]];
        m0 = fmaxf(m0, lrelu(av.x + ad.x));
        m1 = fmaxf(m1, lrelu(av.y + ad.y));
        m2 = fmaxf(m2, lrelu(av.z + ad.z));
        m3 = fmaxf(m3, lrelu(av.w + ad.w));
    }
#pragma unroll
    for (int off = 32; off; off >>= 1) {
        m0 = fmaxf(m0, __shfl_xor(m0, off));
        m1 = fmaxf(m1, __shfl_xor(m1, off));
        m2 = fmaxf(m2, __shfl_xor(m2, off));
        m3 = fmaxf(m3, __shfl_xor(m3, off));
    }

    // pass 2: stage (s,w) in LDS; 2 edges per wave-iteration, float4/lane
    int c = lane & 31;       // col group: cols 4c..4c+3
    int pair = lane >> 5;    // which of the 2 edges this half-wave handles
    int h = c >> 3;          // head of these cols
    float4 acc = make_float4(0.f, 0.f, 0.f, 0.f);
    float d0 = 0.f, d1 = 0.f, d2 = 0.f, d3 = 0.f;
    for (int base = beg; base < end; base += 64) {
        int i = base + lane;
        int cnt = end - base; if (cnt > 64) cnt = 64;
        if (i < end) {
            int s = esrc[i];
            float4 av = ((const float4*)as_)[s];
            float w0 = __expf(lrelu(av.x + ad.x) - m0);
            float w1 = __expf(lrelu(av.y + ad.y) - m1);
            float w2 = __expf(lrelu(av.z + ad.z) - m2);
            float w3 = __expf(lrelu(av.w + ad.w) - m3);
            d0 += w0; d1 += w1; d2 += w2; d3 += w3;
            float sf = __int_as_float(s);
            sw[0 * SWSTR + lane] = make_float2(sf, w0);
            sw[1 * SWSTR + lane] = make_float2(sf, w1);
            sw[2 * SWSTR + lane] = make_float2(sf, w2);
            sw[3 * SWSTR + lane] = make_float2(sf, w3);
        }
        int iters = (cnt + 1) >> 1;
        for (int it = 0; it < iters; ++it) {
            int j = 2 * it + pair;
            float2 swv = sw[h * SWSTR + j];
            float wj = (j < cnt) ? swv.y : 0.f;
            int sj = (j < cnt) ? __float_as_int(swv.x) : 0;
            float4 v = ((const float4*)xw)[(size_t)sj * 32 + c];
            acc.x = fmaf(wj, v.x, acc.x);
            acc.y = fmaf(wj, v.y, acc.y);
            acc.z = fmaf(wj, v.z, acc.z);
            acc.w = fmaf(wj, v.w, acc.w);
        }
    }
    // combine the two half-wave accumulators (lane l and l+32 hold same cols)
    acc.x += __shfl_xor(acc.x, 32);
    acc.y += __shfl_xor(acc.y, 32);
    acc.z += __shfl_xor(acc.z, 32);
    acc.w += __shfl_xor(acc.w, 32);
#pragma unroll
    for (int off = 32; off; off >>= 1) {
        d0 += __shfl_xor(d0, off);
        d1 += __shfl_xor(d1, off);
        d2 += __shfl_xor(d2, off);
        d3 += __shfl_xor(d3, off);
    }
    if (lane < 32) {
        float dn = h == 0 ? d0 : (h == 1 ? d1 : (h == 2 ? d2 : d3));
        float4 bb = ((const float4*)bias)[c];
        float4 o;
        o.x = acc.x / dn + bb.x;
        o.y = acc.y / dn + bb.y;
        o.z = acc.z / dn + bb.z;
        o.w = acc.w / dn + bb.w;
        o.x = o.x > 0.f ? o.x : expm1f(o.x);
        o.y = o.y > 0.f ? o.y : expm1f(o.y);
        o.z = o.z > 0.f ? o.z : expm1f(o.z);
        o.w = o.w > 0.f ? o.w : expm1f(o.w);
        ((float4*)out)[(size_t)node * 32 + c] = o;
    }
}

// ---------------- pooling + head ----------------
__global__ __launch_bounds__(128) void pool(
    const float* __restrict__ h1, const int* __restrict__ batch,
    float* __restrict__ sums, float* __restrict__ cnts) {
    int j = threadIdx.x;
    int n0 = blockIdx.x * 64;
    int n1 = n0 + 64; if (n1 > NN) n1 = NN;
    if (n0 >= NN) return;
    int cur = batch[n0];
    float local = 0.f;
    int cnt = 0;
    for (int n = n0; n < n1; ++n) {
        int g = batch[n];
        if (g != cur) {
            atomicAdd(&sums[cur * HC + j], local);
            if (j == 0) atomicAdd(&cnts[cur], (float)cnt);
            local = 0.f; cnt = 0; cur = g;
        }
        local += h1[(size_t)n * HC + j];
        ++cnt;
    }
    atomicAdd(&sums[cur * HC + j], local);
    if (j == 0) atomicAdd(&cnts[cur], (float)cnt);
}

__global__ __launch_bounds__(128) void head_out(
    const float* __restrict__ sums, const float* __restrict__ cnts,
    const float* __restrict__ lin_w, const float* __restrict__ lin_b,
    float* __restrict__ out) {
    int g = blockIdx.x;
    int j = threadIdx.x;
    float c = cnts[g];
    c = c > 1.f ? c : 1.f;
    float v = sums[g * HC + j] / c * lin_w[j];
    __shared__ float red[HC];
    red[j] = v;
    __syncthreads();
    for (int off = 64; off > 0; off >>= 1) {
        if (j < off) red[j] += red[j + off];
        __syncthreads();
    }
    if (j == 0) out[g] = red[0] + lin_b[0];
}

extern "C" void kernel_launch(void* const* d_in, const int* in_sizes, int n_in,
                              void* d_out, int out_size, void* d_ws, size_t ws_size,
                              hipStream_t stream) {
    const float* x   = (const float*)d_in[0];
    const int*   ei  = (const int*)d_in[1];
    const int*   bat = (const int*)d_in[2];
    const float* W0  = (const float*)d_in[3];
    const float* as0 = (const float*)d_in[4];
    const float* ad0 = (const float*)d_in[5];
    const float* b0  = (const float*)d_in[6];
    const float* W1  = (const float*)d_in[7];
    const float* as1 = (const float*)d_in[8];
    const float* ad1 = (const float*)d_in[9];
    const float* b1  = (const float*)d_in[10];
    const float* lw  = (const float*)d_in[11];
    const float* lb  = (const float*)d_in[12];
    float* out = (float*)d_out;

    char* w = (char*)d_ws;
    float* xw  = (float*)w;  w += (size_t)NN * HC * 4;
    float* h0  = (float*)w;  w += (size_t)NN * HC * 4;
    float* as_ = (float*)w;  w += (size_t)NN * HH * 4;
    float* ad_ = (float*)w;  w += (size_t)NN * HH * 4;
    int* deg       = (int*)w; w += (size_t)NN * 4;
    int* row_start = (int*)w; w += (size_t)(NN + 1) * 4;
    int* cursor    = (int*)w; w += (size_t)NN * 4;
    int* esrc      = (int*)w; w += (size_t)NEDGE * 4;
    float* sums = (float*)w; w += (size_t)GG * HC * 4;
    float* cnts = (float*)w; w += (size_t)GG * 4;

    const int eb = (NEDGE + 255) / 256;
    const int gb = (NN + GMT - 1) / GMT;
    const int ab = (NN + 3) / 4;

    // ---- CSR build (shared by both layers) ----
    hipMemsetAsync(deg, 0, (size_t)NN * 4, stream);
    hist<<<eb, 256, 0, stream>>>(ei, deg);
    scan_deg<<<1, 1024, 0, stream>>>(deg, row_start, cursor);
    scatter<<<eb, 256, 0, stream>>>(ei, cursor, esrc);

    // ---- layer 0 ----
    gemm_alpha<<<gb, 256, 0, stream>>>(x, W0, as0, ad0, xw, as_, ad_);
    aggregate<<<ab, 256, 0, stream>>>(esrc, row_start, as_, ad_, xw, b0, h0);

    // ---- layer 1 ----
    gemm_alpha<<<gb, 256, 0, stream>>>(h0, W1, as1, ad1, xw, as_, ad_);
    aggregate<<<ab, 256, 0, stream>>>(esrc, row_start, as_, ad_, xw, b1, h0);

    // ---- pool + head ----
    hipMemsetAsync(sums, 0, ((size_t)GG * HC + GG) * 4, stream);
    pool<<<(NN + 63) / 64, 128, 0, stream>>>(h0, bat, sums, cnts);
    head_out<<<GG, 128, 0, stream>>>(sums, cnts, lw, lb, out);
}